// Round 2
// baseline (1143.716 us; speedup 1.0000x reference)
//
#include <hip/hip_runtime.h>
#include <cstdint>
#include <cstddef>

// Problem constants
constexpr int HWSZ = 65536;                       // 256*256 pixels per image
constexpr size_t CH_ELEMS = (size_t)304 * HWSZ;   // per-batch 304-channel buffer elems
constexpr int WT_H_ELEMS = 64 * 304;
constexpr int WT_P_ELEMS = 228 * 64;

#define C1F 0.70710678118654752f
#define S2F 1.41421356237309505f

// ---------------- prep: transpose weights for scalar-load GEMMs ----------------
__global__ __launch_bounds__(256) void k_prep(const float* __restrict__ wh,
                                              const float* __restrict__ wp,
                                              float* __restrict__ wt_h,
                                              float* __restrict__ wt_p) {
    int i = blockIdx.x * 256 + threadIdx.x;
    if (i < 64 * 304) {            // wh is [o=304][k=64] -> wt_h[k][o]
        int o = i / 64, k = i % 64;
        wt_h[k * 304 + o] = wh[i];
    }
    int j = i - 64 * 304;
    if (j >= 0 && j < 64 * 228) {  // wp is [o=64][c=228] -> wt_p[c][o]
        int o = j / 228, cc = j % 228;
        wt_p[cc * 64 + o] = wp[j];
    }
}

// ---------------- 1x1 conv (one batch, channel chunk of ngroups*19) ----------------
__global__ __launch_bounds__(256) void k_conv1c(const float* __restrict__ xb,   // [64][65536]
                                                const float* __restrict__ wt,   // [k=64][o=304]
                                                float* __restrict__ chunk,      // [cc][65536]
                                                int c0, int ngroups) {
    int sp = blockIdx.x * 256 + threadIdx.x;   // 0..65535
    float xv[64];
#pragma unroll
    for (int k = 0; k < 64; k++) xv[k] = xb[(size_t)k * HWSZ + sp];
    for (int g = 0; g < ngroups; g++) {
        float acc[19];
#pragma unroll
        for (int i = 0; i < 19; i++) acc[i] = 0.f;
#pragma unroll
        for (int k = 0; k < 64; k++) {
            float xs = xv[k];
            const float* wrow = wt + k * 304 + c0 + g * 19;   // uniform -> s_load
#pragma unroll
            for (int i = 0; i < 19; i++) acc[i] = fmaf(xs, wrow[i], acc[i]);
        }
#pragma unroll
        for (int i = 0; i < 19; i++) chunk[(size_t)(g * 19 + i) * HWSZ + sp] = acc[i];
    }
}

// ---------------- depthwise 3x3, SAME, zero pad (one batch, chunk) ----------------
__global__ __launch_bounds__(256) void k_dwc(const float* __restrict__ chunk,  // [cc][65536]
                                             const float* __restrict__ wdw,    // [304][9]
                                             float* __restrict__ hdwb,         // [304][65536]
                                             int c0) {
    // grid (32, cc): x=row-strip, y=channel-in-chunk
    int ph = blockIdx.x, c = blockIdx.y;
    int t = threadIdx.x;
    __shared__ float tile[10 * 256];
    const float* in = chunk + (size_t)c * HWSZ;
    int r0 = ph * 8 - 1;
    for (int i = t; i < 2560; i += 256) {
        int rr = i >> 8, cc2 = i & 255;
        int gr = r0 + rr;
        tile[i] = (gr >= 0 && gr < 256) ? in[gr * 256 + cc2] : 0.f;
    }
    __syncthreads();
    float w[9];
#pragma unroll
    for (int i = 0; i < 9; i++) w[i] = wdw[(c0 + c) * 9 + i];   // uniform -> s_load
    float cl[10], cm[10], cr_[10];
#pragma unroll
    for (int rr = 0; rr < 10; rr++) {
        cm[rr]  = tile[rr * 256 + t];
        cl[rr]  = (t > 0)   ? tile[rr * 256 + t - 1] : 0.f;
        cr_[rr] = (t < 255) ? tile[rr * 256 + t + 1] : 0.f;
    }
    float* out = hdwb + (size_t)(c0 + c) * HWSZ + (size_t)ph * 8 * 256 + t;
#pragma unroll
    for (int r = 0; r < 8; r++) {
        float s = cl[r] * w[0] + cm[r] * w[1] + cr_[r] * w[2]
                + cl[r + 1] * w[3] + cm[r + 1] * w[4] + cr_[r + 1] * w[5]
                + cl[r + 2] * w[6] + cm[r + 2] * w[7] + cr_[r + 2] * w[8];
        out[(size_t)r * 256] = s;
    }
}

// ---------------- small FFT helpers ----------------
// real FFT-8 (row), unnormalized forward DFT, bins 0..4 (bins 0,4 real)
__device__ __forceinline__ void rfft8(const float a[8], float Xr[5], float Xi[5]) {
    float u0 = a[0] + a[4], u1 = a[0] - a[4];
    float u2 = a[2] + a[6], u3 = a[2] - a[6];
    float u4 = a[1] + a[5], p  = a[1] - a[5];
    float u6 = a[3] + a[7], q  = a[3] - a[7];
    Xr[0] = u0 + u2 + u4 + u6;        Xi[0] = 0.f;
    Xr[1] = u1 + C1F * (p - q);       Xi[1] = -u3 - C1F * (p + q);
    Xr[2] = u0 - u2;                  Xi[2] = -(u4 - u6);
    Xr[3] = u1 - C1F * (p - q);       Xi[3] = u3 - C1F * (p + q);
    Xr[4] = u0 + u2 - u4 - u6;        Xi[4] = 0.f;
}

// real inverse FFT-8 (row), unnormalized; ignores Xi[0], Xi[4] (numpy irfft semantics)
__device__ __forceinline__ void irfft8(const float Xr[5], const float Xi[5], float y[8]) {
    float A = Xr[0], B = Xr[4];
    float cr = Xr[1], ci = Xi[1], dr = Xr[2], di = Xi[2], er = Xr[3], ei = Xi[3];
    float abp = A + B, abm = A - B;
    float ccm = S2F * (cr - ci), ccp = S2F * (cr + ci);
    float eep = S2F * (er + ei), eem = S2F * (er - ei);
    float dr2 = 2.f * dr, di2 = 2.f * di;
    float cep = 2.f * (cr + er);
    float ci2 = 2.f * ci, ei2 = 2.f * ei;
    y[0] = abp + cep + dr2;
    y[1] = abm + ccm - di2 - eep;
    y[2] = abp - dr2 - ci2 + ei2;
    y[3] = abm - ccp + di2 + eem;
    y[4] = abp - cep + dr2;
    y[5] = abm - ccm - di2 + eep;
    y[6] = abp - dr2 + ci2 - ei2;
    y[7] = abm + ccp + di2 - eem;
}

// cross-lane complex FFT-8 over lanes r=0..7 (xor groups), DIF forward,
// output scrambled: lane r holds bin bitrev3(r)
__device__ __forceinline__ void cfwd(float& zr, float& zi, int r) {
    float or_ = __shfl_xor(zr, 4), oi_ = __shfl_xor(zi, 4);
    if (r < 4) { zr += or_; zi += oi_; }
    else {
        float tr = or_ - zr, ti = oi_ - zi;
        int m = r & 3;
        if (m == 0)      { zr = tr;              zi = ti; }
        else if (m == 1) { zr = C1F * (tr + ti); zi = C1F * (ti - tr); }
        else if (m == 2) { zr = ti;              zi = -tr; }
        else             { zr = C1F * (ti - tr); zi = -C1F * (tr + ti); }
    }
    or_ = __shfl_xor(zr, 2); oi_ = __shfl_xor(zi, 2);
    if ((r & 2) == 0) { zr += or_; zi += oi_; }
    else {
        float tr = or_ - zr, ti = oi_ - zi;
        if (r & 1) { zr = ti; zi = -tr; } else { zr = tr; zi = ti; }
    }
    or_ = __shfl_xor(zr, 1); oi_ = __shfl_xor(zi, 1);
    if ((r & 1) == 0) { zr += or_; zi += oi_; }
    else { zr = or_ - zr; zi = oi_ - zi; }
}

// cross-lane complex inverse FFT-8, DIT, scrambled input -> natural order, unnormalized
__device__ __forceinline__ void cinv(float& zr, float& zi, int r) {
    float or_ = __shfl_xor(zr, 1), oi_ = __shfl_xor(zi, 1);
    if ((r & 1) == 0) { zr += or_; zi += oi_; }
    else { zr = or_ - zr; zi = oi_ - zi; }
    or_ = __shfl_xor(zr, 2); oi_ = __shfl_xor(zi, 2);
    if ((r & 2) == 0) {
        if (r & 1) { zr -= oi_; zi += or_; }      // z += i*o
        else       { zr += or_; zi += oi_; }
    } else {
        if (r & 1) { float nr = or_ + zi, ni = oi_ - zr; zr = nr; zi = ni; } // z = o - i*z
        else       { zr = or_ - zr; zi = oi_ - zi; }
    }
    or_ = __shfl_xor(zr, 4); oi_ = __shfl_xor(zi, 4);
    int m = r & 3;
    if (r < 4) {   // z += w*o, w = e^{+i pi m/4}
        if (m == 0)      { zr += or_;                zi += oi_; }
        else if (m == 1) { zr += C1F * (or_ - oi_);  zi += C1F * (or_ + oi_); }
        else if (m == 2) { zr -= oi_;                zi += or_; }
        else             { zr += C1F * (-or_ - oi_); zi += C1F * (or_ - oi_); }
    } else {       // z = o - w*z
        float wr, wi;
        if (m == 0)      { wr = zr;                 wi = zi; }
        else if (m == 1) { wr = C1F * (zr - zi);    wi = C1F * (zr + zi); }
        else if (m == 2) { wr = -zi;                wi = zr; }
        else             { wr = C1F * (-zr - zi);   wi = C1F * (zr - zi); }
        zr = or_ - wr; zi = oi_ - wi;
    }
}

// ---------------- FFT attention per 8x8 patch (one batch); in-place over q/k/v ----------------
__global__ __launch_bounds__(256) void k_fftb(float* __restrict__ hdwb,
                                              const float* __restrict__ fft_param) {
    // grid (32, 76): x=patch-row ph, y=channel c
    int ph = blockIdx.x, c = blockIdx.y;
    int t = threadIdx.x;
    int p = t >> 3, r = t & 7;                          // patch in strip, row in patch
    int br = ((r & 1) << 2) | (r & 2) | (r >> 2);       // bitrev3(r)
    size_t base = (size_t)c * HWSZ + (size_t)(ph * 8 + r) * 256 + p * 8;
    float* qp = hdwb + base;
    float* kp = hdwb + base + (size_t)76 * HWSZ;
    float* vp = hdwb + base + (size_t)152 * HWSZ;

    float a[8], Qr[5], Qi[5], Kr[5], Ki[5], Vr[5], Vi[5];
    {   float4 f0 = *(const float4*)qp, f1 = *(const float4*)(qp + 4);
        a[0]=f0.x; a[1]=f0.y; a[2]=f0.z; a[3]=f0.w; a[4]=f1.x; a[5]=f1.y; a[6]=f1.z; a[7]=f1.w;
        rfft8(a, Qr, Qi); }
    {   float4 f0 = *(const float4*)kp, f1 = *(const float4*)(kp + 4);
        a[0]=f0.x; a[1]=f0.y; a[2]=f0.z; a[3]=f0.w; a[4]=f1.x; a[5]=f1.y; a[6]=f1.z; a[7]=f1.w;
        rfft8(a, Kr, Ki); }
    {   float4 f0 = *(const float4*)vp, f1 = *(const float4*)(vp + 4);
        a[0]=f0.x; a[1]=f0.y; a[2]=f0.z; a[3]=f0.w; a[4]=f1.x; a[5]=f1.y; a[6]=f1.z; a[7]=f1.w;
        rfft8(a, Vr, Vi); }

#pragma unroll
    for (int v = 0; v < 5; v++) { cfwd(Qr[v], Qi[v], r); cfwd(Kr[v], Ki[v], r); cfwd(Vr[v], Vi[v], r); }

    const float inv64 = 0.015625f;
#pragma unroll
    for (int v = 0; v < 5; v++) {
        float pf = fft_param[(c * 8 + br) * 5 + v];
        float vr = Vr[v] * pf, vi = Vi[v] * pf;
        float qr = Qr[v], qi = Qi[v], kr = Kr[v], ki = Ki[v];
        float cr = qr * kr + qi * ki;          // qf * conj(kf)
        float ci = qi * kr - qr * ki;
        float m2q = cr * cr + ci * ci, m2v = vr * vr + vi * vi;
        float rq = rsqrtf(fmaxf(m2q, 1e-38f));
        float rv = rsqrtf(fmaxf(m2v, 1e-38f));
        float s  = sqrtf(m2v) * rq * inv64;    // |vf|/|qck| / 64
        float tt = sqrtf(m2q) * rv * inv64;    // |qck|/|vf| / 64
        Qr[v] = cr * s;      Qi[v] = ci * s;       // out1 = |vf| * unit(qck)
        Vr[v] = vr * tt;     Vi[v] = vi * tt;      // out2 = |qck| * unit(vf)
        Kr[v] = cr * inv64;  Ki[v] = ci * inv64;   // out3 = qck
    }

#pragma unroll
    for (int v = 0; v < 5; v++) { cinv(Qr[v], Qi[v], r); cinv(Vr[v], Vi[v], r); cinv(Kr[v], Ki[v], r); }

    float y[8];
    irfft8(Qr, Qi, y);
    { float4 f0 = {y[0],y[1],y[2],y[3]}, f1 = {y[4],y[5],y[6],y[7]};
      *(float4*)qp = f0; *(float4*)(qp + 4) = f1; }
    irfft8(Vr, Vi, y);
    { float4 f0 = {y[0],y[1],y[2],y[3]}, f1 = {y[4],y[5],y[6],y[7]};
      *(float4*)kp = f0; *(float4*)(kp + 4) = f1; }
    irfft8(Kr, Ki, y);
    { float4 f0 = {y[0],y[1],y[2],y[3]}, f1 = {y[4],y[5],y[6],y[7]};
      *(float4*)vp = f0; *(float4*)(vp + 4) = f1; }
}

// ---------------- layernorm + gate + final projection (one batch) ----------------
__global__ __launch_bounds__(256) void k_outb(const float* __restrict__ hdwb,
                                              const float* __restrict__ wt_p, // [c=228][o=64]
                                              const float* __restrict__ ln1w, const float* __restrict__ ln1b,
                                              const float* __restrict__ ln2w, const float* __restrict__ ln2b,
                                              const float* __restrict__ ln3w, const float* __restrict__ ln3b,
                                              float* __restrict__ outb) {
    int sp = blockIdx.x * 256 + threadIdx.x;   // 0..65535
    const float* hb = hdwb + sp;
    float s1 = 0, q1 = 0, s2 = 0, q2 = 0, s3 = 0, q3 = 0;
    for (int c = 0; c < 76; c++) {
        float v1 = hb[(size_t)c * HWSZ];
        float v2 = hb[(size_t)(76 + c) * HWSZ];
        float v3 = hb[(size_t)(152 + c) * HWSZ];
        s1 += v1; q1 += v1 * v1;
        s2 += v2; q2 += v2 * v2;
        s3 += v3; q3 += v3 * v3;
    }
    const float invE = 1.f / 76.f;
    float m1 = s1 * invE, m2 = s2 * invE, m3 = s3 * invE;
    float r1 = rsqrtf(fmaxf(q1 * invE - m1 * m1, 0.f) + 1e-5f);
    float r2 = rsqrtf(fmaxf(q2 * invE - m2 * m2, 0.f) + 1e-5f);
    float r3 = rsqrtf(fmaxf(q3 * invE - m3 * m3, 0.f) + 1e-5f);
    float acc[64];
#pragma unroll
    for (int o = 0; o < 64; o++) acc[o] = 0.f;
    for (int c = 0; c < 76; c++) {
        float vv = hb[(size_t)(228 + c) * HWSZ];
        float v1 = ((hb[(size_t)c * HWSZ]         - m1) * r1 * ln1w[c] + ln1b[c]) * vv;
        float v2 = ((hb[(size_t)(76 + c) * HWSZ]  - m2) * r2 * ln2w[c] + ln2b[c]) * vv;
        float v3 = ((hb[(size_t)(152 + c) * HWSZ] - m3) * r3 * ln3w[c] + ln3b[c]) * vv;
        const float* w1 = wt_p + c * 64;            // uniform -> s_load
        const float* w2 = wt_p + (76 + c) * 64;
        const float* w3 = wt_p + (152 + c) * 64;
#pragma unroll
        for (int o = 0; o < 64; o++)
            acc[o] += v1 * w1[o] + v2 * w2[o] + v3 * w3[o];
    }
    float* ob = outb + sp;
#pragma unroll
    for (int o = 0; o < 64; o++) ob[(size_t)o * HWSZ] = acc[o];
}

extern "C" void kernel_launch(void* const* d_in, const int* in_sizes, int n_in,
                              void* d_out, int out_size, void* d_ws, size_t ws_size,
                              hipStream_t stream) {
    const float* x    = (const float*)d_in[0];
    const float* wh   = (const float*)d_in[1];
    const float* wdw  = (const float*)d_in[2];
    const float* wp   = (const float*)d_in[3];
    const float* fftp = (const float*)d_in[4];
    const float* ln1w = (const float*)d_in[5];
    const float* ln1b = (const float*)d_in[6];
    const float* ln2w = (const float*)d_in[7];
    const float* ln2b = (const float*)d_in[8];
    const float* ln3w = (const float*)d_in[9];
    const float* ln3b = (const float*)d_in[10];
    float* out = (float*)d_out;
    float* ws  = (float*)d_ws;

    const size_t wbytes = (size_t)(WT_H_ELEMS + WT_P_ELEMS) * 4;
    const size_t need_full  = (CH_ELEMS + CH_ELEMS) * 4 + wbytes;            // ~159.7 MB
    const size_t need_chunk = (CH_ELEMS + (size_t)76 * HWSZ) * 4 + wbytes;   // ~99.8 MB

    int chunk_ch;
    if (ws_size >= need_full)       chunk_ch = 304;   // one conv+dw pair per batch
    else if (ws_size >= need_chunk) chunk_ch = 76;    // 4 conv+dw pairs per batch
    else return;  // insufficient workspace: fail cleanly (diagnostic for next round)

    float* hdwb     = ws;                                   // [304][65536] per-batch
    float* chunkbuf = ws + CH_ELEMS;                        // [chunk_ch][65536]
    float* wt_h     = chunkbuf + (size_t)chunk_ch * HWSZ;   // [64][304]
    float* wt_p     = wt_h + WT_H_ELEMS;                    // [228][64]

    hipLaunchKernelGGL(k_prep, dim3(134), dim3(256), 0, stream, wh, wp, wt_h, wt_p);

    for (int b = 0; b < 2; b++) {
        const float* xb = x + (size_t)b * 64 * HWSZ;
        for (int c0 = 0; c0 < 304; c0 += chunk_ch) {
            hipLaunchKernelGGL(k_conv1c, dim3(256), dim3(256), 0, stream,
                               xb, wt_h, chunkbuf, c0, chunk_ch / 19);
            hipLaunchKernelGGL(k_dwc, dim3(32, chunk_ch), dim3(256), 0, stream,
                               chunkbuf, wdw, hdwb, c0);
        }
        hipLaunchKernelGGL(k_fftb, dim3(32, 76), dim3(256), 0, stream, hdwb, fftp);
        hipLaunchKernelGGL(k_outb, dim3(256), dim3(256), 0, stream, hdwb, wt_p,
                           ln1w, ln1b, ln2w, ln2b, ln3w, ln3b,
                           out + (size_t)b * 64 * HWSZ);
    }
}

// Round 3
// 661.123 us; speedup vs baseline: 1.7300x; 1.7300x over previous
//
#include <hip/hip_runtime.h>
#include <cstdint>
#include <cstddef>

// Problem constants
constexpr int HWSZ = 65536;                       // 256*256 pixels per image
constexpr size_t CH_ELEMS = (size_t)304 * HWSZ;   // per-batch 304-channel buffer elems
constexpr int WT_H_ELEMS = 64 * 304;
constexpr int WT_P_ELEMS = 228 * 64;

#define C1F 0.70710678118654752f
#define S2F 1.41421356237309505f

// ---------------- prep: transpose weights for scalar-load GEMMs ----------------
__global__ __launch_bounds__(256) void k_prep(const float* __restrict__ wh,
                                              const float* __restrict__ wp,
                                              float* __restrict__ wt_h,
                                              float* __restrict__ wt_p) {
    int i = blockIdx.x * 256 + threadIdx.x;
    if (i < 64 * 304) {            // wh is [o=304][k=64] -> wt_h[k][o]
        int o = i / 64, k = i % 64;
        wt_h[k * 304 + o] = wh[i];
    }
    int j = i - 64 * 304;
    if (j >= 0 && j < 64 * 228) {  // wp is [o=64][c=228] -> wt_p[cc][o]
        int o = j / 228, cc = j % 228;
        wt_p[cc * 64 + o] = wp[j];
    }
}

// ---------------- 1x1 conv (one batch); block = 256 px, 38 out-channels ----------------
__global__ __launch_bounds__(256) void k_conv1c(const float* __restrict__ xb,   // [64][65536]
                                                const float* __restrict__ wt,   // [k=64][o=304]
                                                float* __restrict__ chunk,      // [cc][65536]
                                                int c0) {
    int sp = blockIdx.x * 256 + threadIdx.x;   // 0..65535
    float xv[64];
#pragma unroll
    for (int k = 0; k < 64; k++) xv[k] = xb[(size_t)k * HWSZ + sp];
    for (int h = 0; h < 2; h++) {
        int lbase = blockIdx.y * 38 + h * 19;      // chunk-local channel base
        int gbase = c0 + lbase;                    // global out-channel base
        float acc[19];
#pragma unroll
        for (int i = 0; i < 19; i++) acc[i] = 0.f;
#pragma unroll
        for (int k = 0; k < 64; k++) {
            float xs = xv[k];
            const float* wrow = wt + k * 304 + gbase;   // uniform -> s_load
#pragma unroll
            for (int i = 0; i < 19; i++) acc[i] = fmaf(xs, wrow[i], acc[i]);
        }
#pragma unroll
        for (int i = 0; i < 19; i++) chunk[(size_t)(lbase + i) * HWSZ + sp] = acc[i];
    }
}

// ---------------- depthwise 3x3, SAME, zero pad (one batch, chunk) ----------------
__global__ __launch_bounds__(256) void k_dwc(const float* __restrict__ chunk,  // [cc][65536]
                                             const float* __restrict__ wdw,    // [304][9]
                                             float* __restrict__ hdwb,         // [304][65536]
                                             int c0) {
    // grid (32, cc): x=row-strip, y=channel-in-chunk
    int ph = blockIdx.x, c = blockIdx.y;
    int t = threadIdx.x;
    __shared__ float tile[10 * 256];
    const float* in = chunk + (size_t)c * HWSZ;
    int r0 = ph * 8 - 1;
    for (int i = t; i < 2560; i += 256) {
        int rr = i >> 8, cc2 = i & 255;
        int gr = r0 + rr;
        tile[i] = (gr >= 0 && gr < 256) ? in[gr * 256 + cc2] : 0.f;
    }
    __syncthreads();
    float w[9];
#pragma unroll
    for (int i = 0; i < 9; i++) w[i] = wdw[(c0 + c) * 9 + i];   // uniform -> s_load
    float cl[10], cm[10], cr_[10];
#pragma unroll
    for (int rr = 0; rr < 10; rr++) {
        cm[rr]  = tile[rr * 256 + t];
        cl[rr]  = (t > 0)   ? tile[rr * 256 + t - 1] : 0.f;
        cr_[rr] = (t < 255) ? tile[rr * 256 + t + 1] : 0.f;
    }
    float* out = hdwb + (size_t)(c0 + c) * HWSZ + (size_t)ph * 8 * 256 + t;
#pragma unroll
    for (int r = 0; r < 8; r++) {
        float s = cl[r] * w[0] + cm[r] * w[1] + cr_[r] * w[2]
                + cl[r + 1] * w[3] + cm[r + 1] * w[4] + cr_[r + 1] * w[5]
                + cl[r + 2] * w[6] + cm[r + 2] * w[7] + cr_[r + 2] * w[8];
        out[(size_t)r * 256] = s;
    }
}

// ---------------- small FFT helpers ----------------
// real FFT-8 (row), unnormalized forward DFT, bins 0..4 (bins 0,4 real)
__device__ __forceinline__ void rfft8(const float a[8], float Xr[5], float Xi[5]) {
    float u0 = a[0] + a[4], u1 = a[0] - a[4];
    float u2 = a[2] + a[6], u3 = a[2] - a[6];
    float u4 = a[1] + a[5], p  = a[1] - a[5];
    float u6 = a[3] + a[7], q  = a[3] - a[7];
    Xr[0] = u0 + u2 + u4 + u6;        Xi[0] = 0.f;
    Xr[1] = u1 + C1F * (p - q);       Xi[1] = -u3 - C1F * (p + q);
    Xr[2] = u0 - u2;                  Xi[2] = -(u4 - u6);
    Xr[3] = u1 - C1F * (p - q);       Xi[3] = u3 - C1F * (p + q);
    Xr[4] = u0 + u2 - u4 - u6;        Xi[4] = 0.f;
}

// real inverse FFT-8 (row), unnormalized; ignores Xi[0], Xi[4] (numpy irfft semantics)
__device__ __forceinline__ void irfft8(const float Xr[5], const float Xi[5], float y[8]) {
    float A = Xr[0], B = Xr[4];
    float cr = Xr[1], ci = Xi[1], dr = Xr[2], di = Xi[2], er = Xr[3], ei = Xi[3];
    float abp = A + B, abm = A - B;
    float ccm = S2F * (cr - ci), ccp = S2F * (cr + ci);
    float eep = S2F * (er + ei), eem = S2F * (er - ei);
    float dr2 = 2.f * dr, di2 = 2.f * di;
    float cep = 2.f * (cr + er);
    float ci2 = 2.f * ci, ei2 = 2.f * ei;
    y[0] = abp + cep + dr2;
    y[1] = abm + ccm - di2 - eep;
    y[2] = abp - dr2 - ci2 + ei2;
    y[3] = abm - ccp + di2 + eem;
    y[4] = abp - cep + dr2;
    y[5] = abm - ccm - di2 + eep;
    y[6] = abp - dr2 + ci2 - ei2;
    y[7] = abm + ccp + di2 - eem;
}

// cross-lane complex FFT-8 over lanes r=0..7 (xor groups), DIF forward,
// output scrambled: lane r holds bin bitrev3(r)
__device__ __forceinline__ void cfwd(float& zr, float& zi, int r) {
    float or_ = __shfl_xor(zr, 4), oi_ = __shfl_xor(zi, 4);
    if (r < 4) { zr += or_; zi += oi_; }
    else {
        float tr = or_ - zr, ti = oi_ - zi;
        int m = r & 3;
        if (m == 0)      { zr = tr;              zi = ti; }
        else if (m == 1) { zr = C1F * (tr + ti); zi = C1F * (ti - tr); }
        else if (m == 2) { zr = ti;              zi = -tr; }
        else             { zr = C1F * (ti - tr); zi = -C1F * (tr + ti); }
    }
    or_ = __shfl_xor(zr, 2); oi_ = __shfl_xor(zi, 2);
    if ((r & 2) == 0) { zr += or_; zi += oi_; }
    else {
        float tr = or_ - zr, ti = oi_ - zi;
        if (r & 1) { zr = ti; zi = -tr; } else { zr = tr; zi = ti; }
    }
    or_ = __shfl_xor(zr, 1); oi_ = __shfl_xor(zi, 1);
    if ((r & 1) == 0) { zr += or_; zi += oi_; }
    else { zr = or_ - zr; zi = oi_ - zi; }
}

// cross-lane complex inverse FFT-8, DIT, scrambled input -> natural order, unnormalized
__device__ __forceinline__ void cinv(float& zr, float& zi, int r) {
    float or_ = __shfl_xor(zr, 1), oi_ = __shfl_xor(zi, 1);
    if ((r & 1) == 0) { zr += or_; zi += oi_; }
    else { zr = or_ - zr; zi = oi_ - zi; }
    or_ = __shfl_xor(zr, 2); oi_ = __shfl_xor(zi, 2);
    if ((r & 2) == 0) {
        if (r & 1) { zr -= oi_; zi += or_; }      // z += i*o
        else       { zr += or_; zi += oi_; }
    } else {
        if (r & 1) { float nr = or_ + zi, ni = oi_ - zr; zr = nr; zi = ni; } // z = o - i*z
        else       { zr = or_ - zr; zi = oi_ - zi; }
    }
    or_ = __shfl_xor(zr, 4); oi_ = __shfl_xor(zi, 4);
    int m = r & 3;
    if (r < 4) {   // z += w*o, w = e^{+i pi m/4}
        if (m == 0)      { zr += or_;                zi += oi_; }
        else if (m == 1) { zr += C1F * (or_ - oi_);  zi += C1F * (or_ + oi_); }
        else if (m == 2) { zr -= oi_;                zi += or_; }
        else             { zr += C1F * (-or_ - oi_); zi += C1F * (or_ - oi_); }
    } else {       // z = o - w*z
        float wr, wi;
        if (m == 0)      { wr = zr;                 wi = zi; }
        else if (m == 1) { wr = C1F * (zr - zi);    wi = C1F * (zr + zi); }
        else if (m == 2) { wr = -zi;                wi = zr; }
        else             { wr = C1F * (-zr - zi);   wi = C1F * (zr - zi); }
        zr = or_ - wr; zi = oi_ - wi;
    }
}

// ---------------- FFT attention per 8x8 patch (one batch); in-place over q/k/v ----------------
__global__ __launch_bounds__(256) void k_fftb(float* __restrict__ hdwb,
                                              const float* __restrict__ fft_param) {
    // grid (32, 76): x=patch-row ph, y=channel c
    int ph = blockIdx.x, c = blockIdx.y;
    int t = threadIdx.x;
    int p = t >> 3, r = t & 7;                          // patch in strip, row in patch
    int br = ((r & 1) << 2) | (r & 2) | (r >> 2);       // bitrev3(r)
    size_t base = (size_t)c * HWSZ + (size_t)(ph * 8 + r) * 256 + p * 8;
    float* qp = hdwb + base;
    float* kp = hdwb + base + (size_t)76 * HWSZ;
    float* vp = hdwb + base + (size_t)152 * HWSZ;

    float a[8], Qr[5], Qi[5], Kr[5], Ki[5], Vr[5], Vi[5];
    {   float4 f0 = *(const float4*)qp, f1 = *(const float4*)(qp + 4);
        a[0]=f0.x; a[1]=f0.y; a[2]=f0.z; a[3]=f0.w; a[4]=f1.x; a[5]=f1.y; a[6]=f1.z; a[7]=f1.w;
        rfft8(a, Qr, Qi); }
    {   float4 f0 = *(const float4*)kp, f1 = *(const float4*)(kp + 4);
        a[0]=f0.x; a[1]=f0.y; a[2]=f0.z; a[3]=f0.w; a[4]=f1.x; a[5]=f1.y; a[6]=f1.z; a[7]=f1.w;
        rfft8(a, Kr, Ki); }
    {   float4 f0 = *(const float4*)vp, f1 = *(const float4*)(vp + 4);
        a[0]=f0.x; a[1]=f0.y; a[2]=f0.z; a[3]=f0.w; a[4]=f1.x; a[5]=f1.y; a[6]=f1.z; a[7]=f1.w;
        rfft8(a, Vr, Vi); }

#pragma unroll
    for (int v = 0; v < 5; v++) { cfwd(Qr[v], Qi[v], r); cfwd(Kr[v], Ki[v], r); cfwd(Vr[v], Vi[v], r); }

    const float inv64 = 0.015625f;
#pragma unroll
    for (int v = 0; v < 5; v++) {
        float pf = fft_param[(c * 8 + br) * 5 + v];
        float vr = Vr[v] * pf, vi = Vi[v] * pf;
        float qr = Qr[v], qi = Qi[v], kr = Kr[v], ki = Ki[v];
        float cr = qr * kr + qi * ki;          // qf * conj(kf)
        float ci = qi * kr - qr * ki;
        float m2q = cr * cr + ci * ci, m2v = vr * vr + vi * vi;
        float rq = rsqrtf(fmaxf(m2q, 1e-38f));
        float rv = rsqrtf(fmaxf(m2v, 1e-38f));
        float s  = sqrtf(m2v) * rq * inv64;    // |vf|/|qck| / 64
        float tt = sqrtf(m2q) * rv * inv64;    // |qck|/|vf| / 64
        Qr[v] = cr * s;      Qi[v] = ci * s;       // out1 = |vf| * unit(qck)
        Vr[v] = vr * tt;     Vi[v] = vi * tt;      // out2 = |qck| * unit(vf)
        Kr[v] = cr * inv64;  Ki[v] = ci * inv64;   // out3 = qck
    }

#pragma unroll
    for (int v = 0; v < 5; v++) { cinv(Qr[v], Qi[v], r); cinv(Vr[v], Vi[v], r); cinv(Kr[v], Ki[v], r); }

    float y[8];
    irfft8(Qr, Qi, y);
    { float4 f0 = {y[0],y[1],y[2],y[3]}, f1 = {y[4],y[5],y[6],y[7]};
      *(float4*)qp = f0; *(float4*)(qp + 4) = f1; }
    irfft8(Vr, Vi, y);
    { float4 f0 = {y[0],y[1],y[2],y[3]}, f1 = {y[4],y[5],y[6],y[7]};
      *(float4*)kp = f0; *(float4*)(kp + 4) = f1; }
    irfft8(Kr, Ki, y);
    { float4 f0 = {y[0],y[1],y[2],y[3]}, f1 = {y[4],y[5],y[6],y[7]};
      *(float4*)vp = f0; *(float4*)(vp + 4) = f1; }
}

// ---------------- layernorm + gate + final projection (one batch) ----------------
// block = 4 waves over 64 pixels; wave w handles LN-stats slice c in [19w,19w+19)
// and output slice o in [16w,16w+16) over all 228 channels.
__global__ __launch_bounds__(256) void k_outb(const float* __restrict__ hdwb,
                                              const float* __restrict__ wt_p, // [c=228][o=64]
                                              const float* __restrict__ ln1w, const float* __restrict__ ln1b,
                                              const float* __restrict__ ln2w, const float* __restrict__ ln2b,
                                              const float* __restrict__ ln3w, const float* __restrict__ ln3b,
                                              float* __restrict__ outb) {
    int lane = threadIdx.x & 63;
    int w = threadIdx.x >> 6;                 // wave id 0..3
    int sp = blockIdx.x * 64 + lane;          // pixel
    const float* hb = hdwb + sp;

    float s1 = 0, q1 = 0, s2 = 0, q2 = 0, s3 = 0, q3 = 0;
    for (int c = w * 19; c < w * 19 + 19; c++) {
        float v1 = hb[(size_t)c * HWSZ];
        float v2 = hb[(size_t)(76 + c) * HWSZ];
        float v3 = hb[(size_t)(152 + c) * HWSZ];
        s1 += v1; q1 += v1 * v1;
        s2 += v2; q2 += v2 * v2;
        s3 += v3; q3 += v3 * v3;
    }
    __shared__ float sred[6][4][64];
    sred[0][w][lane] = s1; sred[1][w][lane] = q1;
    sred[2][w][lane] = s2; sred[3][w][lane] = q2;
    sred[4][w][lane] = s3; sred[5][w][lane] = q3;
    __syncthreads();
    s1 = sred[0][0][lane] + sred[0][1][lane] + sred[0][2][lane] + sred[0][3][lane];
    q1 = sred[1][0][lane] + sred[1][1][lane] + sred[1][2][lane] + sred[1][3][lane];
    s2 = sred[2][0][lane] + sred[2][1][lane] + sred[2][2][lane] + sred[2][3][lane];
    q2 = sred[3][0][lane] + sred[3][1][lane] + sred[3][2][lane] + sred[3][3][lane];
    s3 = sred[4][0][lane] + sred[4][1][lane] + sred[4][2][lane] + sred[4][3][lane];
    q3 = sred[5][0][lane] + sred[5][1][lane] + sred[5][2][lane] + sred[5][3][lane];

    const float invE = 1.f / 76.f;
    float m1 = s1 * invE, m2 = s2 * invE, m3 = s3 * invE;
    float r1 = rsqrtf(fmaxf(q1 * invE - m1 * m1, 0.f) + 1e-5f);
    float r2 = rsqrtf(fmaxf(q2 * invE - m2 * m2, 0.f) + 1e-5f);
    float r3 = rsqrtf(fmaxf(q3 * invE - m3 * m3, 0.f) + 1e-5f);

    int o0 = w * 16;
    float acc[16];
#pragma unroll
    for (int i = 0; i < 16; i++) acc[i] = 0.f;
    for (int c = 0; c < 76; c++) {
        float vv = hb[(size_t)(228 + c) * HWSZ];
        float v1 = ((hb[(size_t)c * HWSZ]         - m1) * r1 * ln1w[c] + ln1b[c]) * vv;
        float v2 = ((hb[(size_t)(76 + c) * HWSZ]  - m2) * r2 * ln2w[c] + ln2b[c]) * vv;
        float v3 = ((hb[(size_t)(152 + c) * HWSZ] - m3) * r3 * ln3w[c] + ln3b[c]) * vv;
        const float* w1 = wt_p + c * 64 + o0;            // uniform -> s_load
        const float* w2 = wt_p + (76 + c) * 64 + o0;
        const float* w3 = wt_p + (152 + c) * 64 + o0;
#pragma unroll
        for (int i = 0; i < 16; i++)
            acc[i] += v1 * w1[i] + v2 * w2[i] + v3 * w3[i];
    }
#pragma unroll
    for (int i = 0; i < 16; i++) outb[(size_t)(o0 + i) * HWSZ + sp] = acc[i];
}

extern "C" void kernel_launch(void* const* d_in, const int* in_sizes, int n_in,
                              void* d_out, int out_size, void* d_ws, size_t ws_size,
                              hipStream_t stream) {
    const float* x    = (const float*)d_in[0];
    const float* wh   = (const float*)d_in[1];
    const float* wdw  = (const float*)d_in[2];
    const float* wp   = (const float*)d_in[3];
    const float* fftp = (const float*)d_in[4];
    const float* ln1w = (const float*)d_in[5];
    const float* ln1b = (const float*)d_in[6];
    const float* ln2w = (const float*)d_in[7];
    const float* ln2b = (const float*)d_in[8];
    const float* ln3w = (const float*)d_in[9];
    const float* ln3b = (const float*)d_in[10];
    float* out = (float*)d_out;
    float* ws  = (float*)d_ws;

    const size_t wbytes = (size_t)(WT_H_ELEMS + WT_P_ELEMS) * 4;
    const size_t need_full  = (CH_ELEMS + CH_ELEMS) * 4 + wbytes;            // ~159.7 MB
    const size_t need_chunk = (CH_ELEMS + (size_t)76 * HWSZ) * 4 + wbytes;   // ~99.8 MB

    int chunk_ch;
    if (ws_size >= need_full)       chunk_ch = 304;
    else if (ws_size >= need_chunk) chunk_ch = 76;
    else return;

    float* hdwb     = ws;                                   // [304][65536] per-batch
    float* chunkbuf = ws + CH_ELEMS;                        // [chunk_ch][65536]
    float* wt_h     = chunkbuf + (size_t)chunk_ch * HWSZ;   // [64][304]
    float* wt_p     = wt_h + WT_H_ELEMS;                    // [228][64]

    hipLaunchKernelGGL(k_prep, dim3(134), dim3(256), 0, stream, wh, wp, wt_h, wt_p);

    for (int b = 0; b < 2; b++) {
        const float* xb = x + (size_t)b * 64 * HWSZ;
        for (int c0 = 0; c0 < 304; c0 += chunk_ch) {
            hipLaunchKernelGGL(k_conv1c, dim3(256, chunk_ch / 38), dim3(256), 0, stream,
                               xb, wt_h, chunkbuf, c0);
            hipLaunchKernelGGL(k_dwc, dim3(32, chunk_ch), dim3(256), 0, stream,
                               chunkbuf, wdw, hdwb, c0);
        }
        hipLaunchKernelGGL(k_fftb, dim3(32, 76), dim3(256), 0, stream, hdwb, fftp);
        hipLaunchKernelGGL(k_outb, dim3(1024), dim3(256), 0, stream, hdwb, wt_p,
                           ln1w, ln1b, ln2w, ln2b, ln3w, ln3b,
                           out + (size_t)b * 64 * HWSZ);
    }
}